// Round 1
// baseline (209.176 us; speedup 1.0000x reference)
//
#include <hip/hip_runtime.h>

#define SS 4096
#define DD 1024
#define LL 16
#define ROWF 1028   // LDS row stride in floats (4 KB + 16 B pad -> breaks 32-way bank alias)

typedef __attribute__((ext_vector_type(8))) short short8;
typedef __attribute__((ext_vector_type(4))) float fl4;

static __device__ __forceinline__ short f2bf(float f) {
    // round-to-nearest-even fp32 -> bf16 (inputs finite)
    unsigned u = __float_as_uint(f);
    u += 0x7FFFu + ((u >> 16) & 1u);
    return (short)(u >> 16);
}

static __device__ __forceinline__ short8 pack8(fl4 a, fl4 b) {
    short8 r;
    r[0] = f2bf(a[0]); r[1] = f2bf(a[1]); r[2] = f2bf(a[2]); r[3] = f2bf(a[3]);
    r[4] = f2bf(b[0]); r[5] = f2bf(b[1]); r[6] = f2bf(b[2]); r[7] = f2bf(b[3]);
    return r;
}

// Async global->LDS DMA: 16B/lane, per-lane src addr, dest = uniform base + lane*16.
static __device__ __forceinline__ void dma16(const float* g, float* l) {
    __builtin_amdgcn_global_load_lds(
        (const __attribute__((address_space(1))) void*)g,
        (__attribute__((address_space(3))) void*)l, 16, 0, 0);
}

// 256 blocks x 512 thr (8 waves, 2 waves/SIMD, 1 block/CU LDS-forced).
// Block owns (b, 128-s segment) = 8 pairs of 16 s. Raw s_barrier + counted
// vmcnt(8): the pair p+1 DMA stays in flight across ALL of pair p's compute
// (no __syncthreads vmcnt(0) drain). Per pair:
//   B0 (buffer free) -> issue DMA p+1 -> vmcnt(8) (pair p landed) -> B1 ->
//   scores: wave wv does K-slice [wv*128,+128), 4 x mfma_16x16x32_bf16 ->
//   scr -> lgkmcnt(0)+B2 -> wave0 combines 8 partials, exp -> e_lds, zacc ->
//   lgkmcnt(0)+B3 -> PV: thread (q=t&255, lg=t>>8) owns d-quad q, l-range
//   lg*8..lg*8+7; fp32 fmac from LDS. ctx = 8 fl4 = 32 VGPRs.
// D layout: col(s)=lane&15, row(l)=(lane>>4)*4+reg  [m89-verified]
__global__ __launch_bounds__(512) void k_main(const float* __restrict__ mem,
                                              const float* __restrict__ summ,
                                              float* __restrict__ part,
                                              float* __restrict__ Zpart) {
    __shared__ float buf[2][16 * ROWF];   // 131.6 KB
    __shared__ float e_lds[16 * LL];      // 1 KB
    __shared__ float scr[8][256];         // 8 KB

    int blk = blockIdx.x;                 // 256 = 8 b x 32 segments
    int b   = blk >> 5;
    int s_base = (blk & 31) << 7;         // 128 s per block
    int t    = threadIdx.x;
    int wv   = t >> 6;                    // 0..7
    int lane = t & 63;
    int o  = lane & 15;
    int qd = lane >> 4;

    const float* gseg = mem + ((size_t)b * SS + s_base) * DD;

    // summ loads FIRST (so their consumption waits vmcnt(8), not vmcnt(0))
    fl4 a0[4], a1[4];
    {
        const float* arow = summ + o * DD + wv * 128 + qd * 8;
        #pragma unroll
        for (int j = 0; j < 4; ++j) {
            a0[j] = *(const fl4*)(arow + j * 32);
            a1[j] = *(const fl4*)(arow + j * 32 + 4);
        }
    }

    // Prologue: DMA pair 0 (wave's share: rows 2wv, 2wv+1; 4 x 1KB chunks each)
    #pragma unroll
    for (int r = 0; r < 2; ++r) {
        int row = wv * 2 + r;
        #pragma unroll
        for (int c = 0; c < 4; ++c)
            dma16(gseg + (size_t)row * DD + c * 256 + lane * 4,
                  &buf[0][row * ROWF + c * 256]);
    }

    // A-frags in registers: wave wv covers K in [wv*128, wv*128+128)
    short8 afr[4];
    #pragma unroll
    for (int j = 0; j < 4; ++j) afr[j] = pack8(a0[j], a1[j]);

    int lg = t >> 8;                      // l-group: 0 -> l=0..7, 1 -> l=8..15
    int q  = t & 255;                     // owned d-quad
    fl4 ctx[8];
    #pragma unroll
    for (int l = 0; l < 8; ++l) ctx[l] = (fl4){0.f, 0.f, 0.f, 0.f};
    fl4 zacc = {0.f, 0.f, 0.f, 0.f};
    const float scale = 0.03125f;         // 1/sqrt(1024)

    for (int p = 0; p < 8; ++p) {
        // B0: prior PV reads of buf[(p+1)&1] done -> safe to DMA into it
        asm volatile("s_waitcnt lgkmcnt(0)" ::: "memory");
        __builtin_amdgcn_s_barrier();
        asm volatile("" ::: "memory");

        if (p < 7) {
            float* nbuf = &buf[(p + 1) & 1][0];
            const float* gp = gseg + (size_t)(p + 1) * 16 * DD;
            #pragma unroll
            for (int r = 0; r < 2; ++r) {
                int row = wv * 2 + r;
                #pragma unroll
                for (int c = 0; c < 4; ++c)
                    dma16(gp + (size_t)row * DD + c * 256 + lane * 4,
                          &nbuf[row * ROWF + c * 256]);
            }
            asm volatile("s_waitcnt vmcnt(8)" ::: "memory");  // pair p landed
        } else {
            asm volatile("s_waitcnt vmcnt(0)" ::: "memory");
        }
        __builtin_amdgcn_s_barrier();     // B1: pair p visible to all waves
        asm volatile("" ::: "memory");

        const float* bbase = &buf[p & 1][0];
        // scores: this wave's K=128 slice
        fl4 acc = {0.f, 0.f, 0.f, 0.f};
        const float* brow = bbase + o * ROWF + wv * 128 + qd * 8;
        #pragma unroll
        for (int j = 0; j < 4; ++j) {
            fl4 f0 = *(const fl4*)(brow + j * 32);
            fl4 f1 = *(const fl4*)(brow + j * 32 + 4);
            acc = __builtin_amdgcn_mfma_f32_16x16x32_bf16(afr[j], pack8(f0, f1),
                                                          acc, 0, 0, 0);
        }
        *(fl4*)&scr[wv][lane * 4] = acc;
        asm volatile("s_waitcnt lgkmcnt(0)" ::: "memory");
        __builtin_amdgcn_s_barrier();     // B2: partials visible
        asm volatile("" ::: "memory");

        if (wv == 0) {
            fl4 sum = {0.f, 0.f, 0.f, 0.f};
            #pragma unroll
            for (int w = 0; w < 8; ++w)
                sum += *(const fl4*)&scr[w][lane * 4];
            fl4 ev;
            #pragma unroll
            for (int r = 0; r < 4; ++r)
                ev[r] = __expf(sum[r] * scale);
            *(fl4*)&e_lds[o * LL + qd * 4] = ev;   // e[s][l]
            zacc += ev;
        }
        asm volatile("s_waitcnt lgkmcnt(0)" ::: "memory");
        __builtin_amdgcn_s_barrier();     // B3: e_lds ready
        asm volatile("" ::: "memory");

        // PV: thread owns d-quad q for l in [lg*8, lg*8+8); fp32 LDS operands
        const float* mrow = bbase + q * 4;
        const fl4* erow = (const fl4*)&e_lds[lg * 8];
        #pragma unroll 4
        for (int s = 0; s < 16; ++s) {
            fl4 m4 = *(const fl4*)(mrow + s * ROWF);
            fl4 e0 = erow[s * 4];         // e_lds[s*16 + lg*8 .. +3] (broadcast)
            fl4 e1 = erow[s * 4 + 1];     // e_lds[s*16 + lg*8+4 .. +7]
            #pragma unroll
            for (int j = 0; j < 4; ++j) {
                ctx[j]     += e0[j] * m4;
                ctx[4 + j] += e1[j] * m4;
            }
        }
    }

    // Epilogue: unnormalized ctx partials (no atomics); layout = [blk][l][d]
    float* pp = part + (size_t)blk * LL * DD + (size_t)(lg * 8) * DD + q * 4;
    #pragma unroll
    for (int l = 0; l < 8; ++l) *(fl4*)(pp + (size_t)l * DD) = ctx[l];

    if (wv == 0) {
        #pragma unroll
        for (int r = 0; r < 4; ++r) {   // sum over 16 s (o); xor 1,2,4,8 in-group
            float v = zacc[r];
            v += __shfl_xor(v, 1, 64);
            v += __shfl_xor(v, 2, 64);
            v += __shfl_xor(v, 4, 64);
            v += __shfl_xor(v, 8, 64);
            zacc[r] = v;
        }
        if (o == 0) *(fl4*)&Zpart[blk * LL + qd * 4] = zacc;  // lanes 0,16,32,48
    }
}

// out[b][d] = sum_l (w[l] / sum_seg Zpart) * sum_seg part[b*32+seg][l][d]
__global__ __launch_bounds__(256) void k_out(const float* __restrict__ part,
                                             const float* __restrict__ Zpart,
                                             const float* __restrict__ w,
                                             float* __restrict__ out) {
    int blkid = blockIdx.x;          // 128 = 8 b x 16 d-chunks of 64
    int b  = blkid >> 4;
    int d0 = (blkid & 15) << 6;
    int t = threadIdx.x;
    __shared__ float coef[LL];
    __shared__ float red[4][64];

    if (t < LL) {
        float Z = 0.f;
        #pragma unroll
        for (int s = 0; s < 32; ++s) Z += Zpart[(b * 32 + s) * LL + t];
        coef[t] = w[t] / Z;
    }
    __syncthreads();

    int dd = t & 63, cg = t >> 6;    // 4 groups x 8 segments
    float acc = 0.f;
    for (int seg = cg * 8; seg < cg * 8 + 8; ++seg) {
        const float* pb = part + (size_t)(b * 32 + seg) * LL * DD + d0 + dd;
        #pragma unroll
        for (int l = 0; l < LL; ++l) acc += coef[l] * pb[(size_t)l * DD];
    }
    red[cg][dd] = acc;
    __syncthreads();
    if (t < 64) out[b * DD + d0 + t] = red[0][t] + red[1][t] + red[2][t] + red[3][t];
}

extern "C" void kernel_launch(void* const* d_in, const int* in_sizes, int n_in,
                              void* d_out, int out_size, void* d_ws, size_t ws_size,
                              hipStream_t stream) {
    const float* mem  = (const float*)d_in[0];  // [8,4096,1024] fp32
    const float* summ = (const float*)d_in[1];  // [16,1024] fp32
    const float* w    = (const float*)d_in[2];  // [1,16] fp32
    float* out = (float*)d_out;                 // [8,1024] fp32

    char* ws = (char*)d_ws;
    float* Zpart = (float*)ws;                  // 256*16 fl = 16 KB (pad to 64K)
    float* part  = (float*)(ws + 64 * 1024);    // 256*16*1024 fl = 16 MB

    k_main<<<256, 512, 0, stream>>>(mem, summ, part, Zpart);
    k_out<<<128, 256, 0, stream>>>(part, Zpart, w, out);
}

// Round 2
// 204.400 us; speedup vs baseline: 1.0234x; 1.0234x over previous
//
#include <hip/hip_runtime.h>

#define SS 4096
#define DD 1024
#define LL 16
#define ROWF 1028   // LDS row stride in floats (4 KB + 16 B pad -> breaks 32-way bank alias)

typedef __attribute__((ext_vector_type(8))) short short8;
typedef __attribute__((ext_vector_type(4))) float fl4;

static __device__ __forceinline__ short f2bf(float f) {
    // round-to-nearest-even fp32 -> bf16 (inputs finite)
    unsigned u = __float_as_uint(f);
    u += 0x7FFFu + ((u >> 16) & 1u);
    return (short)(u >> 16);
}

static __device__ __forceinline__ short8 pack8(fl4 a, fl4 b) {
    short8 r;
    r[0] = f2bf(a[0]); r[1] = f2bf(a[1]); r[2] = f2bf(a[2]); r[3] = f2bf(a[3]);
    r[4] = f2bf(b[0]); r[5] = f2bf(b[1]); r[6] = f2bf(b[2]); r[7] = f2bf(b[3]);
    return r;
}

// Async global->LDS DMA: 16B/lane, per-lane src addr, dest = uniform base + lane*16.
static __device__ __forceinline__ void dma16(const float* g, float* l) {
    __builtin_amdgcn_global_load_lds(
        (const __attribute__((address_space(1))) void*)g,
        (__attribute__((address_space(3))) void*)l, 16, 0, 0);
}

// 256 blocks x 512 thr (8 waves, 2 waves/SIMD, 1 block/CU LDS-forced).
// Block owns (b, 128-s segment) = 8 pairs of 16 s. Raw s_barrier + counted
// vmcnt(8): pair p+1's DMA stays in flight across ALL of pair p's compute.
// Per pair:
//   B0 (other buffer free) -> issue DMA p+1 -> vmcnt(8) (pair p landed) -> B1
//   -> scores: wave wv K-slice [wv*128,+128), 4 x mfma_16x16x32_bf16 -> scr
//   -> lgkmcnt(0)+B2 -> DISTRIBUTED softmax: threads 0..255 each do one
//   (s,l): sum 8 partials + exp -> e_lds, z += e (per-thread Z) ->
//   lgkmcnt(0)+B3 -> PV: thread (q=t&255, lg=t>>8) owns d-quad q, l-range
//   lg*8..+7; fp32 fmac from LDS. ctx = 8 fl4 = 32 VGPRs.
// MFMA D layout: col(s)=lane&15, row(l)=(lane>>4)*4+reg  [m89-verified]
__global__ __launch_bounds__(512) void k_main(const float* __restrict__ mem,
                                              const float* __restrict__ summ,
                                              float* __restrict__ part,
                                              float* __restrict__ Zpart) {
    __shared__ float buf[2][16 * ROWF];   // 131.6 KB
    __shared__ float e_lds[16 * LL];      // 1 KB
    __shared__ float scr[8][256];         // 8 KB

    int blk = blockIdx.x;                 // 256 = 8 b x 32 segments
    int b   = blk >> 5;
    int s_base = (blk & 31) << 7;         // 128 s per block
    int t    = threadIdx.x;
    int wv   = t >> 6;                    // 0..7
    int lane = t & 63;
    int o  = lane & 15;
    int qd = lane >> 4;

    const float* gseg = mem + ((size_t)b * SS + s_base) * DD;

    // summ loads FIRST (issued before pair-0 DMAs -> their consumption waits
    // a counted vmcnt, not a drain)
    fl4 a0[4], a1[4];
    {
        const float* arow = summ + o * DD + wv * 128 + qd * 8;
        #pragma unroll
        for (int j = 0; j < 4; ++j) {
            a0[j] = *(const fl4*)(arow + j * 32);
            a1[j] = *(const fl4*)(arow + j * 32 + 4);
        }
    }

    // Prologue: DMA pair 0 (wave's share: rows 2wv, 2wv+1; 4 x 1KB chunks each)
    #pragma unroll
    for (int r = 0; r < 2; ++r) {
        int row = wv * 2 + r;
        #pragma unroll
        for (int c = 0; c < 4; ++c)
            dma16(gseg + (size_t)row * DD + c * 256 + lane * 4,
                  &buf[0][row * ROWF + c * 256]);
    }

    // A-frags in registers: wave wv covers K in [wv*128, wv*128+128)
    short8 afr[4];
    #pragma unroll
    for (int j = 0; j < 4; ++j) afr[j] = pack8(a0[j], a1[j]);

    int lg = t >> 8;                      // l-group: 0 -> l=0..7, 1 -> l=8..15
    int q  = t & 255;                     // owned d-quad
    // distributed-softmax role (threads 0..255): s_sm = t&15, l_sm = t>>4
    int s_sm = t & 15;
    int l_sm = (t >> 4) & 15;
    int scr_idx = ((l_sm >> 2) * 16 + s_sm) * 4 + (l_sm & 3);  // scr[.][lane'*4+r]

    fl4 ctx[8];
    #pragma unroll
    for (int l = 0; l < 8; ++l) ctx[l] = (fl4){0.f, 0.f, 0.f, 0.f};
    float z = 0.f;                        // per-thread Z partial (threads <256)
    const float scale = 0.03125f;         // 1/sqrt(1024)

    for (int p = 0; p < 8; ++p) {
        // B0: prior PV reads of buf[(p+1)&1] complete -> safe to DMA into it
        asm volatile("s_waitcnt lgkmcnt(0)" ::: "memory");
        __builtin_amdgcn_s_barrier();
        __builtin_amdgcn_sched_barrier(0);

        if (p < 7) {
            float* nbuf = &buf[(p + 1) & 1][0];
            const float* gp = gseg + (size_t)(p + 1) * 16 * DD;
            #pragma unroll
            for (int r = 0; r < 2; ++r) {
                int row = wv * 2 + r;
                #pragma unroll
                for (int c = 0; c < 4; ++c)
                    dma16(gp + (size_t)row * DD + c * 256 + lane * 4,
                          &nbuf[row * ROWF + c * 256]);
            }
            asm volatile("s_waitcnt vmcnt(8)" ::: "memory");  // pair p landed
        } else {
            asm volatile("s_waitcnt vmcnt(0)" ::: "memory");
        }
        __builtin_amdgcn_sched_barrier(0);
        __builtin_amdgcn_s_barrier();     // B1: pair p visible to all waves
        __builtin_amdgcn_sched_barrier(0);

        const float* bbase = &buf[p & 1][0];
        // scores: this wave's K=128 slice
        fl4 acc = {0.f, 0.f, 0.f, 0.f};
        const float* brow = bbase + o * ROWF + wv * 128 + qd * 8;
        #pragma unroll
        for (int j = 0; j < 4; ++j) {
            fl4 f0 = *(const fl4*)(brow + j * 32);
            fl4 f1 = *(const fl4*)(brow + j * 32 + 4);
            acc = __builtin_amdgcn_mfma_f32_16x16x32_bf16(afr[j], pack8(f0, f1),
                                                          acc, 0, 0, 0);
        }
        *(fl4*)&scr[wv][lane * 4] = acc;
        asm volatile("s_waitcnt lgkmcnt(0)" ::: "memory");
        __builtin_amdgcn_s_barrier();     // B2: partials visible
        __builtin_amdgcn_sched_barrier(0);

        // Distributed softmax: 256 threads, one (s,l) each
        if (t < 256) {
            float sum = 0.f;
            #pragma unroll
            for (int w = 0; w < 8; ++w) sum += scr[w][scr_idx];
            float ev = __expf(sum * scale);
            e_lds[s_sm * LL + l_sm] = ev;
            z += ev;
        }
        asm volatile("s_waitcnt lgkmcnt(0)" ::: "memory");
        __builtin_amdgcn_s_barrier();     // B3: e_lds ready
        __builtin_amdgcn_sched_barrier(0);

        // PV: thread owns d-quad q for l in [lg*8, lg*8+8); fp32 LDS operands
        const float* mrow = bbase + q * 4;
        const fl4* erow = (const fl4*)&e_lds[lg * 8];
        #pragma unroll 4
        for (int s = 0; s < 16; ++s) {
            fl4 m4 = *(const fl4*)(mrow + s * ROWF);
            fl4 e0 = erow[s * 4];         // e_lds[s*16 + lg*8 .. +3] (broadcast)
            fl4 e1 = erow[s * 4 + 1];     // e_lds[s*16 + lg*8+4 .. +7]
            #pragma unroll
            for (int j = 0; j < 4; ++j) {
                ctx[j]     += e0[j] * m4;
                ctx[4 + j] += e1[j] * m4;
            }
        }
    }

    // Epilogue: unnormalized ctx partials (no atomics); layout = [blk][l][d]
    float* pp = part + (size_t)blk * LL * DD + (size_t)(lg * 8) * DD + q * 4;
    #pragma unroll
    for (int l = 0; l < 8; ++l) *(fl4*)(pp + (size_t)l * DD) = ctx[l];

    // Z: threads 0..255 hold z for (s_sm, l_sm); reduce over s within each
    // 16-lane group; lane with s_sm==0 writes Zpart[blk*16 + l_sm]
    if (t < 256) {
        float v = z;
        v += __shfl_xor(v, 1, 64);
        v += __shfl_xor(v, 2, 64);
        v += __shfl_xor(v, 4, 64);
        v += __shfl_xor(v, 8, 64);
        if (s_sm == 0) Zpart[blk * LL + l_sm] = v;
    }
}

// out[b][d] = sum_l (w[l] / sum_seg Zpart) * sum_seg part[b*32+seg][l][d]
// 256 blocks x 256 thr; fl4 loads (16B/lane)
__global__ __launch_bounds__(256) void k_out(const float* __restrict__ part,
                                             const float* __restrict__ Zpart,
                                             const float* __restrict__ w,
                                             float* __restrict__ out) {
    int blkid = blockIdx.x;          // 256 = 8 b x 32 d-chunks of 32
    int b  = blkid >> 5;
    int d0 = (blkid & 31) << 5;
    int t = threadIdx.x;
    __shared__ float coef[LL];
    __shared__ fl4 red[32][8];       // [seg][d-quad]

    if (t < LL) {
        float Z = 0.f;
        #pragma unroll
        for (int s = 0; s < 32; ++s) Z += Zpart[(b * 32 + s) * LL + t];
        coef[t] = w[t] / Z;
    }
    __syncthreads();

    int dq  = t & 7;                 // d-quad within 32-d chunk
    int seg = t >> 3;                // 0..31
    const float* pb = part + (size_t)(b * 32 + seg) * LL * DD + d0 + dq * 4;
    fl4 acc = {0.f, 0.f, 0.f, 0.f};
    #pragma unroll
    for (int l = 0; l < LL; ++l) {
        fl4 v = *(const fl4*)(pb + (size_t)l * DD);
        float c = coef[l];
        acc += c * v;
    }
    red[seg][dq] = acc;
    __syncthreads();

    if (t < 8) {
        fl4 s = {0.f, 0.f, 0.f, 0.f};
        #pragma unroll
        for (int g = 0; g < 32; ++g) s += red[g][t];
        *(fl4*)&out[b * DD + d0 + t * 4] = s;
    }
}

extern "C" void kernel_launch(void* const* d_in, const int* in_sizes, int n_in,
                              void* d_out, int out_size, void* d_ws, size_t ws_size,
                              hipStream_t stream) {
    const float* mem  = (const float*)d_in[0];  // [8,4096,1024] fp32
    const float* summ = (const float*)d_in[1];  // [16,1024] fp32
    const float* w    = (const float*)d_in[2];  // [1,16] fp32
    float* out = (float*)d_out;                 // [8,1024] fp32

    char* ws = (char*)d_ws;
    float* Zpart = (float*)ws;                  // 256*16 fl = 16 KB (pad to 64K)
    float* part  = (float*)(ws + 64 * 1024);    // 256*16*1024 fl = 16 MB

    k_main<<<256, 512, 0, stream>>>(mem, summ, part, Zpart);
    k_out<<<256, 256, 0, stream>>>(part, Zpart, w, out);
}